// Round 1
// baseline (418.480 us; speedup 1.0000x reference)
//
#include <hip/hip_runtime.h>

#define T_PTS 8192
#define D_DIM 128
#define C_OUT 16
#define NSPLIT 4
#define MT 64
#define NT 64
#define JSPAN (T_PTS / NSPLIT) /* 2048 */
#define NJT (JSPAN / NT)       /* 32 */
#define LSTR 132               /* padded LDS row stride in floats (132*4B, 16B aligned) */

// ---------------------------------------------------------------- sq = rowwise sum of squares
__global__ void sq_kernel(const float* __restrict__ X, float* __restrict__ sq) {
    const int wave = threadIdx.x >> 6;
    const int lane = threadIdx.x & 63;
    const int row = blockIdx.x * 4 + wave;
    const float2* xr = (const float2*)(X + row * D_DIM);
    float2 v = xr[lane];
    float s = v.x * v.x + v.y * v.y;
#pragma unroll
    for (int off = 32; off > 0; off >>= 1) s += __shfl_down(s, off, 64);
    if (lane == 0) sq[row] = s;
}

// ---------------------------------------------------------------- fused fp32 "GEMM" + per-row top-2
__launch_bounds__(256, 2)
__global__ void nn_kernel(const float* __restrict__ X, const float* __restrict__ sq,
                          float* __restrict__ candKey, int* __restrict__ candIdx) {
    __shared__ float As[MT * LSTR];
    __shared__ float Bs[NT * LSTR];
    __shared__ float sqs[NT];

    const int tid = threadIdx.x;
    const int tr = tid >> 4;  // 0..15
    const int tc = tid & 15;  // 0..15
    const int r0 = blockIdx.x * MT;
    const int sp = blockIdx.y;
    const int j0 = sp * JSPAN;

    // A tile: rows r0..r0+63, 128 floats each, coalesced float4
    {
        const float4* src = (const float4*)(X + r0 * D_DIM);
#pragma unroll
        for (int it = 0; it < 8; ++it) {
            int f = tid + it * 256;              // 0..2047
            int row = f >> 5, k4 = f & 31;
            *(float4*)(As + row * LSTR + k4 * 4) = src[row * 32 + k4];
        }
    }

    float bk0[4], bk1[4];
    int bi0[4], bi1[4];
#pragma unroll
    for (int m = 0; m < 4; ++m) { bk0[m] = bk1[m] = 1e30f; bi0[m] = bi1[m] = 0x7fffffff; }

    for (int jt = 0; jt < NJT; ++jt) {
        const int jbase = j0 + jt * NT;
        __syncthreads();
        {
            const float4* src = (const float4*)(X + jbase * D_DIM);
#pragma unroll
            for (int it = 0; it < 8; ++it) {
                int f = tid + it * 256;
                int row = f >> 5, k4 = f & 31;
                *(float4*)(Bs + row * LSTR + k4 * 4) = src[row * 32 + k4];
            }
            if (tid < NT) sqs[tid] = sq[jbase + tid];
        }
        __syncthreads();

        float acc[4][4];
#pragma unroll
        for (int m = 0; m < 4; ++m)
#pragma unroll
            for (int n = 0; n < 4; ++n) acc[m][n] = 0.f;

#pragma unroll 4
        for (int kq = 0; kq < 32; ++kq) {
            float4 a[4], b[4];
#pragma unroll
            for (int m = 0; m < 4; ++m)
                a[m] = *(const float4*)(As + (tr + 16 * m) * LSTR + kq * 4);
#pragma unroll
            for (int n = 0; n < 4; ++n)
                b[n] = *(const float4*)(Bs + (tc + 16 * n) * LSTR + kq * 4);
#pragma unroll
            for (int m = 0; m < 4; ++m)
#pragma unroll
                for (int n = 0; n < 4; ++n) {
                    acc[m][n] += a[m].x * b[n].x;
                    acc[m][n] += a[m].y * b[n].y;
                    acc[m][n] += a[m].z * b[n].z;
                    acc[m][n] += a[m].w * b[n].w;
                }
        }

        // key = sq[j] - 2*dot  (order == order of d2; sq[i] is a monotone shift)
#pragma unroll
        for (int m = 0; m < 4; ++m) {
            const int i = r0 + tr + 16 * m;
#pragma unroll
            for (int n = 0; n < 4; ++n) {
                const int j = jbase + tc + 16 * n;
                const float key = sqs[tc + 16 * n] - 2.f * acc[m][n];
                if (j != i) {
                    bool lt0 = (key < bk0[m]) || (key == bk0[m] && j < bi0[m]);
                    bool lt1 = (key < bk1[m]) || (key == bk1[m] && j < bi1[m]);
                    if (lt0) { bk1[m] = bk0[m]; bi1[m] = bi0[m]; bk0[m] = key; bi0[m] = j; }
                    else if (lt1) { bk1[m] = key; bi1[m] = j; }
                }
            }
        }
    }

    // merge the 16 tc-threads per row via LDS scratch (reuse As/Bs)
    __syncthreads();
    float* skey = As;       // 64*16*2 = 2048 floats
    int* sidx = (int*)Bs;   // 2048 ints
#pragma unroll
    for (int m = 0; m < 4; ++m) {
        int rl = tr + 16 * m;
        skey[rl * 32 + tc * 2 + 0] = bk0[m];
        skey[rl * 32 + tc * 2 + 1] = bk1[m];
        sidx[rl * 32 + tc * 2 + 0] = bi0[m];
        sidx[rl * 32 + tc * 2 + 1] = bi1[m];
    }
    __syncthreads();
    if (tid < MT) {
        float k0 = 1e30f, k1 = 1e30f;
        int i0 = 0x7fffffff, i1 = 0x7fffffff;
        for (int t = 0; t < 32; ++t) {
            float k = skey[tid * 32 + t];
            int j = sidx[tid * 32 + t];
            bool lt0 = (k < k0) || (k == k0 && j < i0);
            bool lt1 = (k < k1) || (k == k1 && j < i1);
            if (lt0) { k1 = k0; i1 = i0; k0 = k; i0 = j; }
            else if (lt1) { k1 = k; i1 = j; }
        }
        const int grow = r0 + tid;
        candKey[(sp * T_PTS + grow) * 2 + 0] = k0;
        candKey[(sp * T_PTS + grow) * 2 + 1] = k1;
        candIdx[(sp * T_PTS + grow) * 2 + 0] = i0;
        candIdx[(sp * T_PTS + grow) * 2 + 1] = i1;
    }
}

// ---------------------------------------------------------------- merge splits -> nbrs[i][0..1]
__global__ void merge_kernel(const float* __restrict__ candKey, const int* __restrict__ candIdx,
                             int* __restrict__ nbrs) {
    const int i = blockIdx.x * 256 + threadIdx.x;
    float k0 = 1e30f, k1 = 1e30f;
    int i0 = 0x7fffffff, i1 = 0x7fffffff;
#pragma unroll
    for (int s = 0; s < NSPLIT; ++s)
#pragma unroll
        for (int c = 0; c < 2; ++c) {
            float k = candKey[(s * T_PTS + i) * 2 + c];
            int j = candIdx[(s * T_PTS + i) * 2 + c];
            bool lt0 = (k < k0) || (k == k0 && j < i0);
            bool lt1 = (k < k1) || (k == k1 && j < i1);
            if (lt0) { k1 = k0; i1 = i0; k0 = k; i0 = j; }
            else if (lt1) { k1 = k; i1 = j; }
        }
    nbrs[i * 2 + 0] = i0;
    nbrs[i * 2 + 1] = i1;
}

// ---------------------------------------------------------------- Y = X@W + b; also logits rows [0,T)
__launch_bounds__(256)
__global__ void y_kernel(const float* __restrict__ X, const float* __restrict__ W,
                         const float* __restrict__ b, float* __restrict__ Y,
                         float* __restrict__ out) {
    __shared__ float Xs[16 * LSTR];
    __shared__ float Ws[D_DIM * C_OUT];
    const int tid = threadIdx.x;
    const int r0 = blockIdx.x * 16;
    const float4* src = (const float4*)(X + r0 * D_DIM);
#pragma unroll
    for (int it = 0; it < 2; ++it) {
        int f = tid + it * 256;  // 0..511
        int row = f >> 5, k4 = f & 31;
        *(float4*)(Xs + row * LSTR + k4 * 4) = src[row * 32 + k4];
    }
#pragma unroll
    for (int it = 0; it < 2; ++it) {
        int f = tid + it * 256;
        ((float4*)Ws)[f] = ((const float4*)W)[f];
    }
    __syncthreads();
    const int r = tid >> 4, c = tid & 15;
    float s = b[c];
#pragma unroll
    for (int d = 0; d < D_DIM; ++d) s += Xs[r * LSTR + d] * Ws[d * C_OUT + c];
    const int row = r0 + r;
    Y[row * C_OUT + c] = s;
    out[row * C_OUT + c] = s;
}

// ---------------------------------------------------------------- synthetic rows: lerp of Y
__global__ void syn_kernel(const float* __restrict__ Y, const int* __restrict__ nbrs,
                           const int* __restrict__ nn_idx, const float* __restrict__ gaps,
                           float* __restrict__ out) {
    const int idx = blockIdx.x * 256 + threadIdx.x;  // 0 .. 32768*16
    const int m = idx >> 4;
    const int c = idx & 15;
    const int src = m >> 2;                 // repeat(arange(T), 4)
    const int sel = nn_idx[m];              // 0 or 1
    const int ch = nbrs[src * 2 + sel];
    const float g = gaps[m];
    const float ys = Y[src * C_OUT + c];
    const float yc = Y[ch * C_OUT + c];
    out[(T_PTS + m) * C_OUT + c] = ys + g * (yc - ys);
}

extern "C" void kernel_launch(void* const* d_in, const int* in_sizes, int n_in,
                              void* d_out, int out_size, void* d_ws, size_t ws_size,
                              hipStream_t stream) {
    const float* X = (const float*)d_in[0];
    const int* nn_idx = (const int*)d_in[1];
    const float* gaps = (const float*)d_in[2];
    const float* W = (const float*)d_in[3];
    const float* b = (const float*)d_in[4];
    float* out = (float*)d_out;

    char* ws = (char*)d_ws;
    float* sq = (float*)ws;                                   // 32768 B
    float* candKey = (float*)(ws + 32768);                    // 262144 B
    int* candIdx = (int*)(ws + 32768 + 262144);               // 262144 B
    int* nbrs = (int*)(ws + 32768 + 2 * 262144);              // 65536 B
    float* Y = (float*)(ws + 32768 + 2 * 262144 + 65536);     // 524288 B

    sq_kernel<<<T_PTS / 4, 256, 0, stream>>>(X, sq);
    nn_kernel<<<dim3(T_PTS / MT, NSPLIT), 256, 0, stream>>>(X, sq, candKey, candIdx);
    merge_kernel<<<T_PTS / 256, 256, 0, stream>>>(candKey, candIdx, nbrs);
    y_kernel<<<T_PTS / 16, 256, 0, stream>>>(X, W, b, Y, out);
    syn_kernel<<<(4 * T_PTS * C_OUT) / 256, 256, 0, stream>>>(Y, nbrs, nn_idx, gaps, out);
}

// Round 4
// 175.846 us; speedup vs baseline: 2.3798x; 2.3798x over previous
//
#include <hip/hip_runtime.h>

#define T_PTS 8192
#define D_DIM 128
#define C_OUT 16
#define NSPLIT 8
#define JSPAN (T_PTS / NSPLIT) /* 1024 */
#define NJT (JSPAN / 64)       /* 16 */
#define LB 136                 /* LDS row stride in fp16 (272 B = 17x16B -> b128-friendly) */
#define LSTR 132               /* fp32 LDS stride for y_kernel */
#define NC (NSPLIT * 4)        /* 32 candidates per row */
#define MSTR 65                /* merge scratch row stride */

typedef _Float16 half8 __attribute__((ext_vector_type(8)));
typedef __attribute__((ext_vector_type(4))) float f32x4;
typedef unsigned short ushort_t;

// ---------------------------------------------------------------- fp32 -> fp16 (RNE)
__global__ void cvt_kernel(const float* __restrict__ X, _Float16* __restrict__ Xh) {
    const int f = blockIdx.x * 256 + threadIdx.x;  // one per 8 elements
    const float4 a = ((const float4*)X)[f * 2];
    const float4 b = ((const float4*)X)[f * 2 + 1];
    half8 o;
    o[0] = (_Float16)a.x; o[1] = (_Float16)a.y; o[2] = (_Float16)a.z; o[3] = (_Float16)a.w;
    o[4] = (_Float16)b.x; o[5] = (_Float16)b.y; o[6] = (_Float16)b.z; o[7] = (_Float16)b.w;
    *(half8*)(Xh + f * 8) = o;
}

// ---------------------------------------------------------------- sq = rowwise sum of squares
__global__ void sq_kernel(const float* __restrict__ X, float* __restrict__ sq) {
    const int wave = threadIdx.x >> 6;
    const int lane = threadIdx.x & 63;
    const int row = blockIdx.x * 4 + wave;
    const float2* xr = (const float2*)(X + row * D_DIM);
    float2 v = xr[lane];
    float s = v.x * v.x + v.y * v.y;
#pragma unroll
    for (int off = 32; off > 0; off >>= 1) s += __shfl_down(s, off, 64);
    if (lane == 0) sq[row] = s;
}

// ---------------------------------------------------------------- MFMA fp16 scores + top-4/stream candidates
__launch_bounds__(256, 2)
__global__ void nn_kernel(const _Float16* __restrict__ Xh, const float* __restrict__ sq,
                          ushort_t* __restrict__ cand) {
    __shared__ _Float16 Ash[64 * LB];  // j-tile
    __shared__ _Float16 Bsh[64 * LB];  // i-rows (block-resident)
    __shared__ float sqs[64];

    const int tid = threadIdx.x;
    const int w = tid >> 6;
    const int lane = tid & 63;
    const int quad = lane >> 4;
    const int l15 = lane & 15;
    const int i0 = blockIdx.x * 64;
    const int sp = blockIdx.y;
    const int j0 = sp * JSPAN;

    // stage the 64 i-rows once: 64 rows x 256 B = 1024 x 16B chunks
#pragma unroll
    for (int it = 0; it < 4; ++it) {
        int f = tid + it * 256;  // 0..1023
        int row = f >> 4, ch = f & 15;
        *(uint4*)(Bsh + row * LB + ch * 8) = *(const uint4*)(Xh + (i0 + row) * D_DIM + ch * 8);
    }
    __syncthreads();

    // B-operand frags (i side), fixed for the whole sweep: col n = l15 within n-tile
    half8 bfrag[4][4];
#pragma unroll
    for (int n = 0; n < 4; ++n)
#pragma unroll
        for (int k = 0; k < 4; ++k)
            bfrag[n][k] = *(const half8*)(Bsh + (n * 16 + l15) * LB + k * 32 + quad * 8);

    // explicit (key, j) top-4 chains per n
    float k0[4], k1[4], k2[4], k3[4];
    int j0r[4], j1r[4], j2r[4], j3r[4];
#pragma unroll
    for (int n = 0; n < 4; ++n) {
        k0[n] = k1[n] = k2[n] = k3[n] = 1e30f;
        j0r[n] = j1r[n] = j2r[n] = j3r[n] = 0;
    }
    int icol[4];
#pragma unroll
    for (int n = 0; n < 4; ++n) icol[n] = i0 + n * 16 + l15;

    for (int jt = 0; jt < NJT; ++jt) {
        const int jbase = j0 + jt * 64;
        __syncthreads();
#pragma unroll
        for (int it = 0; it < 4; ++it) {
            int f = tid + it * 256;
            int row = f >> 4, ch = f & 15;
            *(uint4*)(Ash + row * LB + ch * 8) = *(const uint4*)(Xh + (jbase + row) * D_DIM + ch * 8);
        }
        if (tid < 16) *(float4*)(sqs + tid * 4) = *(const float4*)(sq + jbase + tid * 4);
        __syncthreads();

        // A-operand frags: this wave's 16 j-rows, m = l15, k = quad*8 + elem
        half8 af[4];
#pragma unroll
        for (int k = 0; k < 4; ++k)
            af[k] = *(const half8*)(Ash + (w * 16 + l15) * LB + k * 32 + quad * 8);

        const f32x4 sq4 = *(const f32x4*)(sqs + w * 16 + quad * 4);
        const int jg = jbase + w * 16 + quad * 4;  // + r

#pragma unroll
        for (int n = 0; n < 4; ++n) {
            f32x4 acc = {0.f, 0.f, 0.f, 0.f};
#pragma unroll
            for (int k = 0; k < 4; ++k)
                acc = __builtin_amdgcn_mfma_f32_16x16x32_f16(af[k], bfrag[n][k], acc, 0, 0, 0);
#pragma unroll
            for (int r = 0; r < 4; ++r) {
                float key = fmaf(-2.f, acc[r], sq4[r]);
                const int j = jg + r;
                if (j == icol[n]) key = 1e30f;  // unconditional self-exclusion
                bool l0 = key < k0[n], l1 = key < k1[n], l2 = key < k2[n], l3 = key < k3[n];
                k3[n] = l2 ? k2[n] : (l3 ? key : k3[n]);
                j3r[n] = l2 ? j2r[n] : (l3 ? j : j3r[n]);
                k2[n] = l1 ? k1[n] : (l2 ? key : k2[n]);
                j2r[n] = l1 ? j1r[n] : (l2 ? j : j2r[n]);
                k1[n] = l0 ? k0[n] : (l1 ? key : k1[n]);
                j1r[n] = l0 ? j0r[n] : (l1 ? j : j1r[n]);
                k0[n] = l0 ? key : k0[n];
                j0r[n] = l0 ? j : j0r[n];
            }
        }
    }

    // merge: 16 streams x top-4 -> per-i top-4 for this split
    __syncthreads();
    float* mk = (float*)Ash;  // 64 rows x MSTR floats = 16640 B <= 17408
    int* mj = (int*)Bsh;
    const int s = w * 4 + quad;
#pragma unroll
    for (int n = 0; n < 4; ++n) {
        const int il = n * 16 + l15;
        const int base = il * MSTR + s * 4;
        mk[base + 0] = k0[n]; mj[base + 0] = j0r[n];
        mk[base + 1] = k1[n]; mj[base + 1] = j1r[n];
        mk[base + 2] = k2[n]; mj[base + 2] = j2r[n];
        mk[base + 3] = k3[n]; mj[base + 3] = j3r[n];
    }
    __syncthreads();
    if (tid < 64) {
        float a0 = 1e30f, a1 = 1e30f, a2 = 1e30f, a3 = 1e30f;
        int b0 = 0, b1 = 0, b2 = 0, b3 = 0;
        for (int e = 0; e < 64; ++e) {
            float k = mk[tid * MSTR + e];
            int j = mj[tid * MSTR + e];
            bool l0 = k < a0, l1 = k < a1, l2 = k < a2, l3 = k < a3;
            a3 = l2 ? a2 : (l3 ? k : a3); b3 = l2 ? b2 : (l3 ? j : b3);
            a2 = l1 ? a1 : (l2 ? k : a2); b2 = l1 ? b1 : (l2 ? j : b2);
            a1 = l0 ? a0 : (l1 ? k : a1); b1 = l0 ? b0 : (l1 ? j : b1);
            a0 = l0 ? k : a0;             b0 = l0 ? j : b0;
        }
        const int gi = i0 + tid;
        ushort_t* c = cand + (sp * T_PTS + gi) * 4;
        c[0] = (ushort_t)b0; c[1] = (ushort_t)b1; c[2] = (ushort_t)b2; c[3] = (ushort_t)b3;
    }
}

// ---------------------------------------------------------------- exact fp32 rescore of 32 candidates
__global__ void rescore_kernel(const float* __restrict__ X, const float* __restrict__ sq,
                               const ushort_t* __restrict__ cand, int* __restrict__ nbrs) {
    __shared__ float keys[8][NC];
    __shared__ int idxs[8][NC];
    const int t = threadIdx.x & 31;
    const int ii = threadIdx.x >> 5;  // 0..7
    const int i = blockIdx.x * 8 + ii;
    {
        const int spc = t >> 2, c = t & 3;
        const int j = (int)cand[(spc * T_PTS + i) * 4 + c];
        const float4* xi = (const float4*)(X + i * D_DIM);
        const float4* xj = (const float4*)(X + j * D_DIM);
        float ssum = 0.f;
#pragma unroll
        for (int q = 0; q < 32; ++q) {
            float4 a = xi[q], b = xj[q];
            ssum += a.x * b.x; ssum += a.y * b.y; ssum += a.z * b.z; ssum += a.w * b.w;
        }
        float key = sq[j] - 2.f * ssum;
        if (j == i) key = 1e30f;
        keys[ii][t] = key;
        idxs[ii][t] = j;
    }
    __syncthreads();
    if (t == 0) {
        float m0 = 1e30f, m1 = 1e30f;
        int n0 = 0x7fffffff, n1 = 0x7fffffff;
        for (int e = 0; e < NC; ++e) {
            float k = keys[ii][e];
            int j = idxs[ii][e];
            bool lt0 = (k < m0) || (k == m0 && j < n0);
            bool lt1 = (k < m1) || (k == m1 && j < n1);
            if (lt0) { m1 = m0; n1 = n0; m0 = k; n0 = j; }
            else if (lt1) { m1 = k; n1 = j; }
        }
        nbrs[i * 2 + 0] = n0;
        nbrs[i * 2 + 1] = n1;
    }
}

// ---------------------------------------------------------------- Y = X@W + b; also logits rows [0,T)
__launch_bounds__(256)
__global__ void y_kernel(const float* __restrict__ X, const float* __restrict__ W,
                         const float* __restrict__ b, float* __restrict__ Y,
                         float* __restrict__ out) {
    __shared__ float Xs[16 * LSTR];
    __shared__ float Ws[D_DIM * C_OUT];
    const int tid = threadIdx.x;
    const int r0 = blockIdx.x * 16;
    const float4* src = (const float4*)(X + r0 * D_DIM);
#pragma unroll
    for (int it = 0; it < 2; ++it) {
        int f = tid + it * 256;  // 0..511
        int row = f >> 5, kq = f & 31;
        *(float4*)(Xs + row * LSTR + kq * 4) = src[row * 32 + kq];
    }
#pragma unroll
    for (int it = 0; it < 2; ++it) {
        int f = tid + it * 256;
        ((float4*)Ws)[f] = ((const float4*)W)[f];
    }
    __syncthreads();
    const int r = tid >> 4, c = tid & 15;
    float s = b[c];
#pragma unroll
    for (int d = 0; d < D_DIM; ++d) s += Xs[r * LSTR + d] * Ws[d * C_OUT + c];
    const int row = r0 + r;
    Y[row * C_OUT + c] = s;
    out[row * C_OUT + c] = s;
}

// ---------------------------------------------------------------- synthetic rows: lerp of Y
__global__ void syn_kernel(const float* __restrict__ Y, const int* __restrict__ nbrs,
                           const int* __restrict__ nn_idx, const float* __restrict__ gaps,
                           float* __restrict__ out) {
    const int idx = blockIdx.x * 256 + threadIdx.x;
    const int m = idx >> 4;
    const int c = idx & 15;
    const int src = m >> 2;       // repeat(arange(T), 4)
    const int sel = nn_idx[m];    // 0 or 1
    const int ch = nbrs[src * 2 + sel];
    const float g = gaps[m];
    const float ys = Y[src * C_OUT + c];
    const float yc = Y[ch * C_OUT + c];
    out[(T_PTS + m) * C_OUT + c] = ys + g * (yc - ys);
}

extern "C" void kernel_launch(void* const* d_in, const int* in_sizes, int n_in,
                              void* d_out, int out_size, void* d_ws, size_t ws_size,
                              hipStream_t stream) {
    const float* X = (const float*)d_in[0];
    const int* nn_idx = (const int*)d_in[1];
    const float* gaps = (const float*)d_in[2];
    const float* W = (const float*)d_in[3];
    const float* b = (const float*)d_in[4];
    float* out = (float*)d_out;

    char* ws = (char*)d_ws;
    _Float16* Xh = (_Float16*)ws;                                  // 2 MB
    float* sq = (float*)(ws + 2097152);                            // 32 KB
    ushort_t* cand = (ushort_t*)(ws + 2097152 + 32768);            // 512 KB
    int* nbrs = (int*)(ws + 2097152 + 32768 + 524288);             // 64 KB
    float* Y = (float*)(ws + 2097152 + 32768 + 524288 + 65536);    // 512 KB

    cvt_kernel<<<(T_PTS * D_DIM / 8) / 256, 256, 0, stream>>>(X, Xh);
    sq_kernel<<<T_PTS / 4, 256, 0, stream>>>(X, sq);
    nn_kernel<<<dim3(T_PTS / 64, NSPLIT), 256, 0, stream>>>(Xh, sq, cand);
    rescore_kernel<<<T_PTS / 8, 256, 0, stream>>>(X, sq, cand, nbrs);
    y_kernel<<<T_PTS / 16, 256, 0, stream>>>(X, W, b, Y, out);
    syn_kernel<<<(4 * T_PTS * C_OUT) / 256, 256, 0, stream>>>(Y, nbrs, nn_idx, gaps, out);
}

// Round 6
// 168.916 us; speedup vs baseline: 2.4774x; 1.0410x over previous
//
#include <hip/hip_runtime.h>

#define T_PTS 8192
#define D_DIM 128
#define C_OUT 16
#define NSPLIT 8
#define JSPAN (T_PTS / NSPLIT) /* 1024 */
#define NJT (JSPAN / 64)       /* 16 */
#define LSTR 132               /* fp32 LDS stride for y part */
#define NC (NSPLIT * 4)        /* 32 candidates per row */
#define MSTR 65                /* merge scratch row stride */
#define RS_BLOCKS 1024         /* rescore blocks (8 rows each) in mid_kernel */

typedef _Float16 half8 __attribute__((ext_vector_type(8)));
typedef __attribute__((ext_vector_type(4))) float f32x4;
typedef unsigned short ushort_t;

// ---------------------------------------------------------------- prep: fp32->fp16 + rowwise sumsq
__global__ void prep_kernel(const float* __restrict__ X, _Float16* __restrict__ Xh,
                            float* __restrict__ sq) {
    const int tid = threadIdx.x;
    const int row = blockIdx.x * 16 + (tid >> 4);
    const int c8 = (tid & 15) * 8;
    const float4* p = (const float4*)(X + row * D_DIM + c8);
    const float4 a = p[0], b = p[1];
    half8 o;
    o[0] = (_Float16)a.x; o[1] = (_Float16)a.y; o[2] = (_Float16)a.z; o[3] = (_Float16)a.w;
    o[4] = (_Float16)b.x; o[5] = (_Float16)b.y; o[6] = (_Float16)b.z; o[7] = (_Float16)b.w;
    *(half8*)(Xh + row * D_DIM + c8) = o;
    float s = a.x * a.x + a.y * a.y + a.z * a.z + a.w * a.w
            + b.x * b.x + b.y * b.y + b.z * b.z + b.w * b.w;
    s += __shfl_xor(s, 1); s += __shfl_xor(s, 2);
    s += __shfl_xor(s, 4); s += __shfl_xor(s, 8);
    if ((tid & 15) == 0) sq[row] = s;
}

// ---------------------------------------------------------------- MFMA fp16 scores, barrier-free
// fp16 keys are CANDIDATE-RECALL ONLY; final ordering is re-derived in fp32 by mid_kernel
// with the exact accumulation order validated in rounds 1/4.
__launch_bounds__(256, 2)
__global__ void nn_kernel(const _Float16* __restrict__ Xh, const float* __restrict__ sq,
                          ushort_t* __restrict__ cand) {
    __shared__ float mk[64 * MSTR];
    __shared__ int mj[64 * MSTR];

    const int tid = threadIdx.x;
    const int w = tid >> 6;
    const int lane = tid & 63;
    const int quad = lane >> 4;
    const int l15 = lane & 15;
    const int i0 = blockIdx.x * 64;
    const int sp = blockIdx.y;
    const int j0 = sp * JSPAN;

    // B-operand frags (i side), loaded straight from global (coalesced; L2-resident)
    half8 bfrag[4][4];
#pragma unroll
    for (int n = 0; n < 4; ++n)
#pragma unroll
        for (int k = 0; k < 4; ++k)
            bfrag[n][k] = *(const half8*)(Xh + (i0 + n * 16 + l15) * D_DIM + k * 32 + quad * 8);

    float mk0[4], mk1[4], mk2[4], mk3[4], sk[4];
    int mj0[4], mj1[4], mj2[4], mj3[4], sj[4];
#pragma unroll
    for (int n = 0; n < 4; ++n) {
        mk0[n] = mk1[n] = mk2[n] = mk3[n] = sk[n] = 1e30f;
        mj0[n] = mj1[n] = mj2[n] = mj3[n] = sj[n] = 0;
    }
    int icol[4];
#pragma unroll
    for (int n = 0; n < 4; ++n) icol[n] = i0 + n * 16 + l15;

    for (int jt = 0; jt < NJT; ++jt) {
        const int jbase = j0 + jt * 64;
        const int jrow = jbase + w * 16 + l15;
        half8 af[4];
#pragma unroll
        for (int k = 0; k < 4; ++k)
            af[k] = *(const half8*)(Xh + jrow * D_DIM + k * 32 + quad * 8);
        const f32x4 sq4 = *(const f32x4*)(sq + jbase + w * 16 + quad * 4);
        const int jg = jbase + w * 16 + quad * 4;  // + r

#pragma unroll
        for (int n = 0; n < 4; ++n) {
            f32x4 acc = {0.f, 0.f, 0.f, 0.f};
#pragma unroll
            for (int k = 0; k < 4; ++k)
                acc = __builtin_amdgcn_mfma_f32_16x16x32_f16(af[k], bfrag[n][k], acc, 0, 0, 0);
            float q0 = fmaf(-2.f, acc[0], sq4[0]);
            float q1 = fmaf(-2.f, acc[1], sq4[1]);
            float q2 = fmaf(-2.f, acc[2], sq4[2]);
            float q3 = fmaf(-2.f, acc[3], sq4[3]);
            if (jg + 0 == icol[n]) q0 = 1e30f;  // self-exclusion BEFORE selection
            if (jg + 1 == icol[n]) q1 = 1e30f;
            if (jg + 2 == icol[n]) q2 = 1e30f;
            if (jg + 3 == icol[n]) q3 = 1e30f;
            // quad top-2 with indices (5-comparator network)
            bool p01 = q1 < q0;
            float lA = p01 ? q1 : q0; int lAj = jg + (p01 ? 1 : 0);
            float hA = p01 ? q0 : q1; int hAj = jg + (p01 ? 0 : 1);
            bool p23 = q3 < q2;
            float lB = p23 ? q3 : q2; int lBj = jg + (p23 ? 3 : 2);
            float hB = p23 ? q2 : q3; int hBj = jg + (p23 ? 2 : 3);
            bool pm = lB < lA;
            float kmin = pm ? lB : lA; int jmin = pm ? lBj : lAj;
            float mm = pm ? lA : lB;   int mmj = pm ? lAj : lBj;
            bool ph = hB < hA;
            float mh = ph ? hB : hA;   int mhj = ph ? hBj : hAj;
            bool ps = mh < mm;
            float ksec = ps ? mh : mm; int jsec = ps ? mhj : mmj;
            // quad-min -> top-4 chain
            {
                bool l0 = kmin < mk0[n], l1 = kmin < mk1[n], l2 = kmin < mk2[n], l3 = kmin < mk3[n];
                mk3[n] = l2 ? mk2[n] : (l3 ? kmin : mk3[n]);
                mj3[n] = l2 ? mj2[n] : (l3 ? jmin : mj3[n]);
                mk2[n] = l1 ? mk1[n] : (l2 ? kmin : mk2[n]);
                mj2[n] = l1 ? mj1[n] : (l2 ? jmin : mj2[n]);
                mk1[n] = l0 ? mk0[n] : (l1 ? kmin : mk1[n]);
                mj1[n] = l0 ? mj0[n] : (l1 ? jmin : mj1[n]);
                mk0[n] = l0 ? kmin : mk0[n];
                mj0[n] = l0 ? jmin : mj0[n];
            }
            // quad-second -> side top-1
            {
                bool ls = ksec < sk[n];
                sk[n] = ls ? ksec : sk[n];
                sj[n] = ls ? jsec : sj[n];
            }
        }
    }

    // fold side chain into main chain (once per stream per n)
#pragma unroll
    for (int n = 0; n < 4; ++n) {
        float v = sk[n]; int jv = sj[n];
        bool l0 = v < mk0[n], l1 = v < mk1[n], l2 = v < mk2[n], l3 = v < mk3[n];
        mk3[n] = l2 ? mk2[n] : (l3 ? v : mk3[n]);
        mj3[n] = l2 ? mj2[n] : (l3 ? jv : mj3[n]);
        mk2[n] = l1 ? mk1[n] : (l2 ? v : mk2[n]);
        mj2[n] = l1 ? mj1[n] : (l2 ? jv : mj2[n]);
        mk1[n] = l0 ? mk0[n] : (l1 ? v : mk1[n]);
        mj1[n] = l0 ? mj0[n] : (l1 ? jv : mj1[n]);
        mk0[n] = l0 ? v : mk0[n];
        mj0[n] = l0 ? jv : mj0[n];
    }

    // merge: 16 streams x top-4 -> per-i top-4 for this split
    const int s = w * 4 + quad;
#pragma unroll
    for (int n = 0; n < 4; ++n) {
        const int il = n * 16 + l15;
        const int base = il * MSTR + s * 4;
        mk[base + 0] = mk0[n]; mj[base + 0] = mj0[n];
        mk[base + 1] = mk1[n]; mj[base + 1] = mj1[n];
        mk[base + 2] = mk2[n]; mj[base + 2] = mj2[n];
        mk[base + 3] = mk3[n]; mj[base + 3] = mj3[n];
    }
    __syncthreads();
    if (tid < 64) {
        float a0 = 1e30f, a1 = 1e30f, a2 = 1e30f, a3 = 1e30f;
        int b0 = 0, b1 = 0, b2 = 0, b3 = 0;
        for (int e = 0; e < 64; ++e) {
            float k = mk[tid * MSTR + e];
            int j = mj[tid * MSTR + e];
            bool l0 = k < a0, l1 = k < a1, l2 = k < a2, l3 = k < a3;
            a3 = l2 ? a2 : (l3 ? k : a3); b3 = l2 ? b2 : (l3 ? j : b3);
            a2 = l1 ? a1 : (l2 ? k : a2); b2 = l1 ? b1 : (l2 ? j : b2);
            a1 = l0 ? a0 : (l1 ? k : a1); b1 = l0 ? b0 : (l1 ? j : b1);
            a0 = l0 ? k : a0;             b0 = l0 ? j : b0;
        }
        const int gi = i0 + tid;
        ushort_t* c = cand + (sp * T_PTS + gi) * 4;
        c[0] = (ushort_t)b0; c[1] = (ushort_t)b1; c[2] = (ushort_t)b2; c[3] = (ushort_t)b3;
    }
}

// ---------------------------------------------------------------- mid: rescore (R4-verbatim arithmetic) + Y=XW+b
// CRITICAL: the rescore dot MUST stay a sequential fma chain (`ssum += a.x*b.x;` x4, loop over q)
// — this accumulation order is what matched the reference in rounds 1 and 4. Any re-association
// (tree sums, shfl butterflies) flips marginal neighbor pairs and fails the harness.
__global__ void mid_kernel(const float* __restrict__ X, const float* __restrict__ sq,
                           const ushort_t* __restrict__ cand, int* __restrict__ nbrs,
                           const float* __restrict__ W, const float* __restrict__ b,
                           float* __restrict__ Y, float* __restrict__ out) {
    __shared__ float keys[8][NC];
    __shared__ int idxs[8][NC];
    __shared__ float Xs[16 * LSTR];
    __shared__ float Ws[D_DIM * C_OUT];
    const int tid = threadIdx.x;

    if (blockIdx.x < RS_BLOCKS) {
        // exact fp32 rescore of 32 candidates: 8 rows/block, 1 thread per (row, candidate)
        const int t = tid & 31;
        const int ii = tid >> 5;  // 0..7
        const int i = blockIdx.x * 8 + ii;
        {
            const int spc = t >> 2, c = t & 3;
            const int j = (int)cand[(spc * T_PTS + i) * 4 + c];
            const float4* xi = (const float4*)(X + i * D_DIM);
            const float4* xj = (const float4*)(X + j * D_DIM);
            float ssum = 0.f;
#pragma unroll
            for (int q = 0; q < 32; ++q) {
                float4 a = xi[q], b2 = xj[q];
                ssum += a.x * b2.x; ssum += a.y * b2.y; ssum += a.z * b2.z; ssum += a.w * b2.w;
            }
            float key = sq[j] - 2.f * ssum;
            if (j == i) key = 1e30f;
            keys[ii][t] = key;
            idxs[ii][t] = j;
        }
        __syncthreads();
        if (t == 0) {
            float m0 = 1e30f, m1 = 1e30f;
            int n0 = 0x7fffffff, n1 = 0x7fffffff;
            for (int e = 0; e < NC; ++e) {
                float k = keys[ii][e];
                int j = idxs[ii][e];
                bool lt0 = (k < m0) || (k == m0 && j < n0);
                bool lt1 = (k < m1) || (k == m1 && j < n1);
                if (lt0) { m1 = m0; n1 = n0; m0 = k; n0 = j; }
                else if (lt1) { m1 = k; n1 = j; }
            }
            nbrs[i * 2 + 0] = n0;
            nbrs[i * 2 + 1] = n1;
        }
    } else {
        // Y = X@W + b, plus logits rows [0,T)
        const int r0 = (blockIdx.x - RS_BLOCKS) * 16;
        const float4* src = (const float4*)(X + r0 * D_DIM);
#pragma unroll
        for (int it = 0; it < 2; ++it) {
            int f = tid + it * 256;  // 0..511
            int row = f >> 5, kq = f & 31;
            *(float4*)(Xs + row * LSTR + kq * 4) = src[row * 32 + kq];
        }
#pragma unroll
        for (int it = 0; it < 2; ++it) {
            int f = tid + it * 256;
            ((float4*)Ws)[f] = ((const float4*)W)[f];
        }
        __syncthreads();
        const int r = tid >> 4, c = tid & 15;
        float s = b[c];
#pragma unroll
        for (int d = 0; d < D_DIM; ++d) s += Xs[r * LSTR + d] * Ws[d * C_OUT + c];
        const int row = r0 + r;
        Y[row * C_OUT + c] = s;
        out[row * C_OUT + c] = s;
    }
}

// ---------------------------------------------------------------- synthetic rows: lerp of Y
__global__ void syn_kernel(const float* __restrict__ Y, const int* __restrict__ nbrs,
                           const int* __restrict__ nn_idx, const float* __restrict__ gaps,
                           float* __restrict__ out) {
    const int idx = blockIdx.x * 256 + threadIdx.x;
    const int m = idx >> 4;
    const int c = idx & 15;
    const int src = m >> 2;       // repeat(arange(T), 4)
    const int sel = nn_idx[m];    // 0 or 1
    const int ch = nbrs[src * 2 + sel];
    const float g = gaps[m];
    const float ys = Y[src * C_OUT + c];
    const float yc = Y[ch * C_OUT + c];
    out[(T_PTS + m) * C_OUT + c] = ys + g * (yc - ys);
}

extern "C" void kernel_launch(void* const* d_in, const int* in_sizes, int n_in,
                              void* d_out, int out_size, void* d_ws, size_t ws_size,
                              hipStream_t stream) {
    const float* X = (const float*)d_in[0];
    const int* nn_idx = (const int*)d_in[1];
    const float* gaps = (const float*)d_in[2];
    const float* W = (const float*)d_in[3];
    const float* b = (const float*)d_in[4];
    float* out = (float*)d_out;

    char* ws = (char*)d_ws;
    _Float16* Xh = (_Float16*)ws;                                  // 2 MB
    float* sq = (float*)(ws + 2097152);                            // 32 KB
    ushort_t* cand = (ushort_t*)(ws + 2097152 + 32768);            // 512 KB
    int* nbrs = (int*)(ws + 2097152 + 32768 + 524288);             // 64 KB
    float* Y = (float*)(ws + 2097152 + 32768 + 524288 + 65536);    // 512 KB

    prep_kernel<<<T_PTS / 16, 256, 0, stream>>>(X, Xh, sq);
    nn_kernel<<<dim3(T_PTS / 64, NSPLIT), 256, 0, stream>>>(Xh, sq, cand);
    mid_kernel<<<RS_BLOCKS + T_PTS / 16, 256, 0, stream>>>(X, sq, cand, nbrs, W, b, Y, out);
    syn_kernel<<<(4 * T_PTS * C_OUT) / 256, 256, 0, stream>>>(Y, nbrs, nn_idx, gaps, out);
}